// Round 2
// 154.794 us; speedup vs baseline: 1.0043x; 1.0043x over previous
//
#include <hip/hip_runtime.h>

// RBF causal attention: out[m] = sum_{j<=m} exp(-0.125*||q_m - k_j||^2) * v_j
// B=2 H=16 S=2048 D=64, fp32 in/out.
// fp16 hi/lo-split QK (3 MFMAs ~ fp32 accuracy), fp16 PV with p scaled 2^14.
// R8 (= R7 + permlane direction fix):
// (a) P LDS round-trip replaced by in-register transpose: fp16 pack +
//     v_permlane32_swap_b32 assembles PV A-frags directly from the QK C-layout
//     (T12 pattern). ISA semantics: swap(vdst,vsrc) exchanges VDST.lanes[32:63]
//     with VSRC.lanes[0:31], so the A-group must be the FIRST operand
//     (R7 had them reversed -> scrambled P -> correctness fail).
// (b) freed 16 KB LDS spent on a double-buffered tile image (2x25600B, still
//     3 blocks/CU): stage(t+1) issued at iteration start into the idle buffer;
//     the single end-of-iter __syncthreads (vmcnt(0)+barrier) lands after
//     ~2000cy of compute -> stage latency off the critical path, one barrier
//     per iter instead of two.
// (c) s_setprio(1) around the MFMA clusters.

constexpr int S_LEN = 2048;
constexpr int HD    = 64;
constexpr int BM    = 128;   // Q rows per block (4 waves x 32 rows)
constexpr int BN    = 64;    // K/V rows per tile
constexpr float SCALE = 0.125f;
constexpr float LOG2E = 1.44269504088896f;
constexpr float C2    = 2.f * SCALE * LOG2E;   // coeff on qk term
constexpr int TS = 25600;    // ws bytes per (bh,jt) tile: Khi 8K|Klo 8K|Vt 8K|ksq 256|pad

typedef _Float16 half8  __attribute__((ext_vector_type(8)));
typedef _Float16 half4  __attribute__((ext_vector_type(4)));
typedef _Float16 half2v __attribute__((ext_vector_type(2)));
typedef float    f32x4  __attribute__((ext_vector_type(4)));
typedef float    f32x16 __attribute__((ext_vector_type(16)));
typedef unsigned int uint4v __attribute__((ext_vector_type(4)));
typedef unsigned int uint2v __attribute__((ext_vector_type(2)));

// 16B-chunk XOR swizzle (rows of 64 halves = 8 chunks of 8 halves).
__device__ __forceinline__ int swz(int row, int chunk) {
  return (row << 3) + (chunk ^ (row & 7));
}

// ---------------- pass 1: preconvert K/V into LDS-image tiles in ws ----------
__global__ __launch_bounds__(256, 4)
void preconvert(const float* __restrict__ Kp, const float* __restrict__ Vp,
                char* __restrict__ ws) {
  const int x  = blockIdx.x;
  const int bh = x >> 5, jt = x & 31;
  const int t  = threadIdx.x;
  const int w  = t >> 6, lane = t & 63;

  char* img = ws + (size_t)(bh * 32 + jt) * TS;
  half8* imgKh = (half8*)img;
  half8* imgKl = imgKh + 512;
  half8* imgVt = imgKh + 1024;
  float* ksqp  = (float*)(img + 24576);

  const float* Kt = Kp + ((size_t)bh * S_LEN + jt * BN) * HD;
  const float* Vt = Vp + ((size_t)bh * S_LEN + jt * BN) * HD;

  #pragma unroll
  for (int i = 0; i < 4; ++i) {
    const int id  = t + 256 * i;
    const int row = id >> 4;
    const int d4  = id & 15;
    const f32x4 f = *(const f32x4*)(Kt + row * HD + d4 * 4);
    half4 hv, lv;
    float ss = 0.f;
    #pragma unroll
    for (int c = 0; c < 4; ++c) {
      const float fv = f[c];
      const _Float16 hi = (_Float16)fv;
      hv[c] = hi;
      lv[c] = (_Float16)(fv - (float)hi);
      ss += fv * fv;
    }
    ((half4*)&imgKh[swz(row, d4 >> 1)])[d4 & 1] = hv;
    ((half4*)&imgKl[swz(row, d4 >> 1)])[d4 & 1] = lv;
    #pragma unroll
    for (int m = 1; m < 16; m <<= 1) ss += __shfl_xor(ss, m);
    if ((t & 15) == 0) ksqp[row] = ss * (SCALE * LOG2E) - 14.0f;  // bias folded
  }
  // V transpose: lane holds col d=lane, rows w*16..w*16+15
  float vr[16];
  #pragma unroll
  for (int i = 0; i < 16; ++i) vr[i] = Vt[(w * 16 + i) * HD + lane];
  half8 v0, v1;
  #pragma unroll
  for (int i = 0; i < 8; ++i) { v0[i] = (_Float16)vr[i]; v1[i] = (_Float16)vr[8 + i]; }
  imgVt[swz(lane, 2 * w + 0)] = v0;
  imgVt[swz(lane, 2 * w + 1)] = v1;
}

// ---------------- main kernel ------------------------------------------------
__global__ __launch_bounds__(256, 3)
void rbf_causal_attn(const float* __restrict__ Qp, const char* __restrict__ ws,
                     float* __restrict__ Op) {
  __shared__ __align__(16) char sTile[2][TS];  // double-buffered Khi|Klo|Vt|ksq image

  const int x    = blockIdx.x;                 // 0..767
  const int xcd  = x & 7;
  const int idx  = x >> 3;                     // 0..95
  const int bh   = xcd * 4 + (idx & 3);        // 4 bh per XCD (L2 reuse of ws)
  const int a    = idx >> 2;                   // arc 0..23
  const int t    = threadIdx.x;
  const int w    = t >> 6;
  const int lane = t & 63;
  const int l31  = lane & 31;
  const int l5   = lane >> 5;                  // 0/1

  // arc: first 8 arcs take 12 j-iters, rest 11 (total 272 per bh)
  const int start = (a < 8) ? 12 * a : 96 + 11 * (a - 8);
  const int len   = (a < 8) ? 12 : 11;

  // flattened (qt descending, jt ascending) -> (qt, jt)
  int rem = start, qt = 15;
  while (rem >= 2 * qt + 2) { rem -= 2 * qt + 2; --qt; }
  int jt = rem;

  const char* wsb = ws + (size_t)bh * 32 * TS;

  half8 qh[4], ql[4];   // B-operand Q frags: lane holds row w*32+l31, k-chunk ks*16+l5*8
  float qsq;            // SCALE*LOG2E*|q_row|^2
  f32x16 oacc[2];       // O accumulator (x 2^14), dtile 0/1
  #pragma unroll
  for (int d = 0; d < 2; ++d)
    #pragma unroll
    for (int e = 0; e < 16; ++e) oacc[d][e] = 0.f;

  auto load_q = [&](int qtile) {
    const float* Qg = Qp + ((size_t)bh * S_LEN + (size_t)qtile * BM + w * 32 + l31) * HD;
    float ss = 0.f;
    #pragma unroll
    for (int ks = 0; ks < 4; ++ks) {
      const int d0 = ks * 16 + l5 * 8;
      const f32x4 fa = *(const f32x4*)(Qg + d0);
      const f32x4 fb = *(const f32x4*)(Qg + d0 + 4);
      half8 h, l;
      #pragma unroll
      for (int c = 0; c < 4; ++c) {
        const float va = fa[c], vb = fb[c];
        const _Float16 ha = (_Float16)va, hb = (_Float16)vb;
        h[c] = ha;  h[c + 4] = hb;
        l[c] = (_Float16)(va - (float)ha);
        l[c + 4] = (_Float16)(vb - (float)hb);
        ss += va * va + vb * vb;
      }
      qh[ks] = h;  ql[ks] = l;
    }
    ss += __shfl_xor(ss, 32);   // combine l5 halves -> full row sum
    qsq = ss * (SCALE * LOG2E);
  };

  auto flush = [&](int qtile) {
    #pragma unroll
    for (int dt = 0; dt < 2; ++dt)
      #pragma unroll
      for (int r = 0; r < 16; ++r) {
        const int row = qtile * BM + w * 32 + (r & 3) + 8 * (r >> 2) + 4 * l5;
        atomicAdd(Op + ((size_t)bh * S_LEN + row) * HD + dt * 32 + l31,
                  oacc[dt][r] * 6.103515625e-05f);   // * 2^-14
      }
  };

  auto zacc = [&]() {
    #pragma unroll
    for (int d = 0; d < 2; ++d)
      #pragma unroll
      for (int e = 0; e < 16; ++e) oacc[d][e] = 0.f;
  };

  // issue global->LDS DMA of tile jtile into buffer p (no wait here)
  auto stage = [&](int p, int jtile) {
    const char* gt = wsb + (size_t)jtile * TS;
    char* dst = sTile[p];
    #pragma unroll
    for (int i = 0; i < 6; ++i) {
      const int off = w * 6144 + i * 1024;
      __builtin_amdgcn_global_load_lds((const unsigned int*)(gt + off + lane * 16),
                                       (unsigned int*)(dst + off), 16, 0, 0);
    }
    if (w == 0)
      __builtin_amdgcn_global_load_lds((const unsigned int*)(gt + 24576 + lane * 16),
                                       (unsigned int*)(dst + 24576), 16, 0, 0);
  };

  // pack two fp32 -> one u32 of 2 x fp16 (RNE, same numerics as before)
  auto pk = [&](float xx, float yy) -> unsigned int {
    half2v h;
    h[0] = (_Float16)xx;
    h[1] = (_Float16)yy;
    return __builtin_bit_cast(unsigned int, h);
  };

  load_q(qt);
  stage(0, jt);
  __syncthreads();             // prologue drain: buffer 0 ready

  bool newq = false;
  #pragma unroll 1
  for (int step = 0; step < len; ++step) {
    const int p = step & 1;

    // next-step tile indices (uniform across block)
    int jn = jt + 1, qn = qt;
    const bool cross = (jn > 2 * qt + 1);
    if (cross) { jn = 0; qn = qt - 1; }

    // issue next tile's DMA into the idle buffer ASAP (hidden under compute)
    if (step + 1 < len) stage(p ^ 1, jn);

    // q-tile boundary bookkeeping (rare; overlaps the in-flight stage)
    if (newq) { flush(qt + 1); zacc(); load_q(qt); newq = false; }

    const half8* bKh  = (const half8*)sTile[p];
    const half8* bKl  = bKh + 512;
    const half8* bVt  = bKh + 1024;
    const float* bksq = (const float*)(sTile[p] + 24576);

    const bool need_mask = (jt >= 2 * qt);
    const int mg = qt * BM + w * 32 + l31;

    #pragma unroll
    for (int ntile = 0; ntile < 2; ++ntile) {
      // ---- S^T = K * Q^T (hi/lo) ----
      f32x16 acc;
      #pragma unroll
      for (int e = 0; e < 16; ++e) acc[e] = 0.f;
      __builtin_amdgcn_s_setprio(1);
      #pragma unroll
      for (int ks = 0; ks < 4; ++ks) {
        const int rr = ntile * 32 + l31;
        const int ch = (2 * ks + l5) ^ (rr & 7);
        const half8 kh = bKh[(rr << 3) + ch];
        const half8 kl = bKl[(rr << 3) + ch];
        acc = __builtin_amdgcn_mfma_f32_32x32x16_f16(kh, qh[ks], acc, 0, 0, 0);
        acc = __builtin_amdgcn_mfma_f32_32x32x16_f16(kh, ql[ks], acc, 0, 0, 0);
        acc = __builtin_amdgcn_mfma_f32_32x32x16_f16(kl, qh[ks], acc, 0, 0, 0);
      }
      __builtin_amdgcn_s_setprio(0);

      // ---- p = exp2(C2*qk - qsq' - ksq') in-place in acc ----
      #pragma unroll
      for (int g = 0; g < 4; ++g) {
        const f32x4 k4 = *(const f32x4*)(bksq + ntile * 32 + 8 * g + 4 * l5);
        #pragma unroll
        for (int rr2 = 0; rr2 < 4; ++rr2) {
          const int reg = g * 4 + rr2;
          const float lg = __builtin_fmaf(C2, acc[reg], -k4[rr2]) - qsq;
          float pv = __builtin_amdgcn_exp2f(lg);
          if (need_mask) {
            const int ng = jt * BN + ntile * 32 + 8 * g + 4 * l5 + rr2;
            if (ng > mg) pv = 0.f;
          }
          acc[reg] = pv;
        }
      }

      // ---- in-register C->A transpose: pack + permlane32_swap, then PV ----
      // acc[r] = P[k_loc=(r&3)+8*(r>>2)+4*l5][q=l31]. PV A-frag for lane
      // (l31,l5) needs P[q=l31][k=16*ks2+8*l5+e], e=0..7:
      //   lanes<32 : [own regs 8ks2..+3            | (lane+32)'s regs 8ks2..+3 ]
      //   lanes>=32: [(lane-32)'s regs 8ks2+4..+7  | own regs 8ks2+4..+7       ]
      // v_permlane32_swap_b32 vdst,vsrc swaps VDST.lanes[32:63]<->VSRC.lanes[0:31],
      // so with vdst=A-group word, vsrc=B-group word:
      //   newA = [ownA | partnerLow_B], newB = [partnerHigh_A | ownB]
      // and pa = {newA0,newA1,newB0,newB1} is exactly the arrangement above.
      #pragma unroll
      for (int ks2 = 0; ks2 < 2; ++ks2) {
        const unsigned int a0 = pk(acc[8 * ks2 + 0], acc[8 * ks2 + 1]);
        const unsigned int a1 = pk(acc[8 * ks2 + 2], acc[8 * ks2 + 3]);
        const unsigned int b0 = pk(acc[8 * ks2 + 4], acc[8 * ks2 + 5]);
        const unsigned int b1 = pk(acc[8 * ks2 + 6], acc[8 * ks2 + 7]);
        const uint2v r0 = __builtin_amdgcn_permlane32_swap(a0, b0, false, false);
        const uint2v r1 = __builtin_amdgcn_permlane32_swap(a1, b1, false, false);
        uint4v wv;
        wv[0] = r0[0];  wv[1] = r1[0];   // own/partner A side (elements 0..3)
        wv[2] = r0[1];  wv[3] = r1[1];   // own/partner B side (elements 4..7)
        const half8 pa = __builtin_bit_cast(half8, wv);

        const int ks = ntile * 2 + ks2;
        __builtin_amdgcn_s_setprio(1);
        #pragma unroll
        for (int dt = 0; dt < 2; ++dt) {
          const int rr = dt * 32 + l31;
          const half8 vt = bVt[(rr << 3) + ((2 * ks + l5) ^ (rr & 7))];
          oacc[dt] = __builtin_amdgcn_mfma_f32_32x32x16_f16(pa, vt, oacc[dt], 0, 0, 0);
        }
        __builtin_amdgcn_s_setprio(0);
      }
    }

    // single barrier per iter: drains this iter's stage DMA (latency already
    // hidden under QK/exp/PV) and protects both LDS buffers.
    __syncthreads();

    jt = jn;
    if (cross) { qt = qn; newq = true; }
  }
  flush(newq ? qt + 1 : qt);
}

extern "C" void kernel_launch(void* const* d_in, const int* in_sizes, int n_in,
                              void* d_out, int out_size, void* d_ws, size_t ws_size,
                              hipStream_t stream) {
  const float* q = (const float*)d_in[0];
  const float* k = (const float*)d_in[1];
  const float* v = (const float*)d_in[2];
  float* o = (float*)d_out;
  hipMemsetAsync(d_out, 0, (size_t)out_size * sizeof(float), stream);
  preconvert<<<dim3(1024), dim3(256), 0, stream>>>(k, v, (char*)d_ws);
  rbf_causal_attn<<<dim3(768), dim3(256), 0, stream>>>(q, (const char*)d_ws, o);
}